// Round 4
// baseline (279.768 us; speedup 1.0000x reference)
//
#include <hip/hip_runtime.h>

// TAM fused kernel round 4: barrier-free, high-occupancy, L2-reuse design.
// C=12, T=10, H*W=28, K=3. One wave per sample, 4 independent waves per
// 256-thread block, persistent grid (1024 blocks x 8 samples/wave).
// No __syncthreads in the hot loop; no 13.4KB sx LDS -- the apply phase
// re-reads x from L2 (reuse distance ~1MB << 4MB/XCD). Weights + folded BN
// staged once per block in LDS.

#define CC 12
#define TT 10
#define SAMPLE 3360
#define EPSF 1e-5f

typedef float f4 __attribute__((ext_vector_type(4)));

// Wave-level LDS producer->consumer sync (single wave, lockstep):
#define WSYNC() do { asm volatile("s_waitcnt lgkmcnt(0)" ::: "memory"); \
                     __builtin_amdgcn_sched_barrier(0); } while (0)

// Per-wave scratch layout (floats). Region A (pcol[840], phases 1-2) is
// unioned with region B (phases 3-6) -- disjoint lifetimes, WSYNC-separated.
#define WS_F    1024
#define OFF_SZ    0     // [240] G hidden           (B)
#define OFF_SA1 240     // [30]  L hidden           (B)
#define OFF_SACT 272    // [120] sigmoid gate       (B)
#define OFF_SW0 400     // [120] fused coef tap0    (B)
#define OFF_SW1 520     // [120] fused coef tap1    (B)
#define OFF_SW2 640     // [120] fused coef tap2    (B)
#define OFF_POOL 840    // [120] pooled[c][t]
#define OFF_SK  960     // [36]  softmax kern k0[12],k1[12],k2[12]

__global__ __launch_bounds__(256, 4) void tam_kernel(
    const float* __restrict__ x,
    const float* __restrict__ w_g1,
    const float* __restrict__ g1_gamma, const float* __restrict__ g1_beta,
    const float* __restrict__ g1_mean,  const float* __restrict__ g1_var,
    const float* __restrict__ w_g2,
    const float* __restrict__ w_l1,
    const float* __restrict__ l1_gamma, const float* __restrict__ l1_beta,
    const float* __restrict__ l1_mean,  const float* __restrict__ l1_var,
    const float* __restrict__ w_l2,
    float* __restrict__ out, int n_total, int iters)
{
    __shared__ float sscr[4 * WS_F];
    __shared__ float wg1[200], wg2[60], wl1[108], wl2[36];
    __shared__ float gsS[20], gbS[20], lsS[3], lbS[3];

    const int tid = threadIdx.x;

    // ---- one-time weight staging + BN folding (single block barrier) ----
    for (int i = tid; i < 200; i += 256) wg1[i] = w_g1[i];
    for (int i = tid; i < 60;  i += 256) wg2[i] = w_g2[i];
    for (int i = tid; i < 108; i += 256) wl1[i] = w_l1[i];
    for (int i = tid; i < 36;  i += 256) wl2[i] = w_l2[i];
    if (tid < 20) {
        const float s = rsqrtf(g1_var[tid] + EPSF) * g1_gamma[tid];
        gsS[tid] = s; gbS[tid] = g1_beta[tid] - g1_mean[tid] * s;
    } else if (tid < 23) {
        const int m = tid - 20;
        const float s = rsqrtf(l1_var[m] + EPSF) * l1_gamma[m];
        lsS[m] = s; lbS[m] = l1_beta[m] - l1_mean[m] * s;
    }
    __syncthreads();

    const int wid  = tid >> 6;
    const int lane = tid & 63;
    float* ws = sscr + wid * WS_F;
    const int gw = blockIdx.x * 4 + wid;

    for (int it = 0; it < iters; ++it) {
        const int n = gw * iters + it;
        if (n >= n_total) break;
        const f4* xg = reinterpret_cast<const f4*>(x + (size_t)n * SAMPLE);
        f4*       og = reinterpret_cast<f4*>(out + (size_t)n * SAMPLE);

        // ---- phase 1: coalesced load burst + per-f4 partial sums -> pcol ----
        f4 r[13];
        #pragma unroll
        for (int k = 0; k < 13; ++k) r[k] = xg[k * 64 + lane];
        f4 rt;
        if (lane < 8) rt = xg[832 + lane];
        #pragma unroll
        for (int k = 0; k < 13; ++k)
            ws[k * 64 + lane] = r[k].x + r[k].y + r[k].z + r[k].w;
        if (lane < 8) ws[832 + lane] = rt.x + rt.y + rt.z + rt.w;
        WSYNC();

        // ---- phase 2: row sums (7 pcol each) -> spool[c*10+t] ----
        {
            const int r0 = lane;
            float s = 0.f;
            #pragma unroll
            for (int i = 0; i < 7; ++i) s += ws[r0 * 7 + i];
            ws[OFF_POOL + r0] = s * (1.0f / 28.0f);
            if (lane < 56) {
                const int r1 = lane + 64;
                float s1 = 0.f;
                #pragma unroll
                for (int i = 0; i < 7; ++i) s1 += ws[r1 * 7 + i];
                ws[OFF_POOL + r1] = s1 * (1.0f / 28.0f);
            }
        }
        WSYNC();

        // ---- phase 3: G hidden (240 tasks) + L conv1 (30 tasks) ----
        #pragma unroll
        for (int q = 0; q < 5; ++q) {
            const int task = lane + q * 64;
            if (task < 240) {
                const int c = task / 20, j = task % 20;
                float s = 0.f;
                #pragma unroll
                for (int t = 0; t < TT; ++t)
                    s += ws[OFF_POOL + c * TT + t] * wg1[j * TT + t];
                ws[OFF_SZ + task] = fmaxf(gsS[j] * s + gbS[j], 0.f);
            } else if (task < 270) {
                const int e = task - 240;
                const int m = e / TT, t = e % TT;
                float s = 0.f;
                #pragma unroll
                for (int c = 0; c < CC; ++c) {
                    #pragma unroll
                    for (int k = 0; k < 3; ++k) {
                        const int t2 = t + k - 1;
                        if (t2 >= 0 && t2 < TT)
                            s += ws[OFF_POOL + c * TT + t2] * wl1[(m * CC + c) * 3 + k];
                    }
                }
                ws[OFF_SA1 + e] = fmaxf(lsS[m] * s + lbS[m], 0.f);
            }
        }
        WSYNC();

        // ---- phase 4: G scores+softmax (12 lanes) + L conv2+sigmoid (120) ----
        if (lane < CC) {
            const int c = lane;
            float sc0 = 0.f, sc1 = 0.f, sc2 = 0.f;
            #pragma unroll
            for (int j = 0; j < 20; ++j) {
                const float zj = ws[OFF_SZ + c * 20 + j];
                sc0 += zj * wg2[j];
                sc1 += zj * wg2[20 + j];
                sc2 += zj * wg2[40 + j];
            }
            const float mx = fmaxf(sc0, fmaxf(sc1, sc2));
            const float e0 = __expf(sc0 - mx), e1 = __expf(sc1 - mx), e2 = __expf(sc2 - mx);
            const float ri = 1.0f / (e0 + e1 + e2);
            ws[OFF_SK + c]      = e0 * ri;
            ws[OFF_SK + 12 + c] = e1 * ri;
            ws[OFF_SK + 24 + c] = e2 * ri;
        }
        #pragma unroll
        for (int q = 0; q < 2; ++q) {
            const int task = lane + q * 64;
            if (task < CC * TT) {
                const int c = task / TT, t = task % TT;
                float s = 0.f;
                #pragma unroll
                for (int m = 0; m < 3; ++m)
                    s += ws[OFF_SA1 + m * TT + t] * wl2[c * 3 + m];
                ws[OFF_SACT + task] = 1.0f / (1.0f + __expf(-s));
            }
        }
        WSYNC();

        // ---- phase 5: fused coefs per (c,t) ----
        #pragma unroll
        for (int q = 0; q < 2; ++q) {
            const int task = lane + q * 64;
            if (task < CC * TT) {
                const int c = task / TT, t = task % TT;
                const float k0 = ws[OFF_SK + c];
                const float k1 = ws[OFF_SK + 12 + c];
                const float k2 = ws[OFF_SK + 24 + c];
                ws[OFF_SW0 + task] = (t > 0) ? k0 * ws[OFF_SACT + c * TT + t - 1] : 0.f;
                ws[OFF_SW1 + task] = k1 * ws[OFF_SACT + c * TT + t];
                ws[OFF_SW2 + task] = (t < 9) ? k2 * ws[OFF_SACT + c * TT + t + 1] : 0.f;
            }
        }
        WSYNC();

        // ---- phase 6: apply via L2 re-read, transposed coalesced NT store ----
        // out f4 vo = t*84 + c*7 + s4 ; taps at x f4 = c*70 + t'*7 + s4.
        #pragma unroll
        for (int k = 0; k < 14; ++k) {
            const int vo = lane + k * 64;
            if (k < 13 || lane < 8) {
                const int t   = vo / 84;
                const int rem = vo % 84;
                const int c   = rem / 7;
                const int s4  = rem % 7;
                const int base = c * 70 + s4;
                const int tm = (t > 0) ? t - 1 : 0;
                const int tp = (t < 9) ? t + 1 : 9;
                const f4 x0 = xg[base + tm * 7];
                const f4 x1 = xg[base + t  * 7];
                const f4 x2 = xg[base + tp * 7];
                const int ct = c * TT + t;
                const float w0 = ws[OFF_SW0 + ct];
                const float w1 = ws[OFF_SW1 + ct];
                const float w2 = ws[OFF_SW2 + ct];
                const f4 acc = w0 * x0 + w1 * x1 + w2 * x2;
                __builtin_nontemporal_store(acc, og + vo);
            }
        }
        WSYNC();  // pcol of next iter overlaps sw regions
    }
}

extern "C" void kernel_launch(void* const* d_in, const int* in_sizes, int n_in,
                              void* d_out, int out_size, void* d_ws, size_t ws_size,
                              hipStream_t stream) {
    (void)n_in; (void)out_size; (void)d_ws; (void)ws_size;
    const float* x        = (const float*)d_in[0];
    const float* w_g1     = (const float*)d_in[1];
    const float* g1_gamma = (const float*)d_in[2];
    const float* g1_beta  = (const float*)d_in[3];
    const float* g1_mean  = (const float*)d_in[4];
    const float* g1_var   = (const float*)d_in[5];
    const float* w_l1     = (const float*)d_in[7];
    const float* w_g2     = (const float*)d_in[6];
    const float* l1_gamma = (const float*)d_in[8];
    const float* l1_beta  = (const float*)d_in[9];
    const float* l1_mean  = (const float*)d_in[10];
    const float* l1_var   = (const float*)d_in[11];
    const float* w_l2     = (const float*)d_in[12];
    float* out = (float*)d_out;

    const int n_total = in_sizes[0] / SAMPLE;     // 32768
    const int blocks  = 1024;                     // persistent, 4 waves each
    const int slots   = blocks * 4;
    const int iters   = (n_total + slots - 1) / slots;  // 8
    tam_kernel<<<blocks, 256, 0, stream>>>(
        x, w_g1, g1_gamma, g1_beta, g1_mean, g1_var, w_g2,
        w_l1, l1_gamma, l1_beta, l1_mean, l1_var, w_l2, out, n_total, iters);
}

// Round 5
// 239.932 us; speedup vs baseline: 1.1660x; 1.1660x over previous
//
#include <hip/hip_runtime.h>

// TAM fused kernel round 5: registers-resident columns, shuffle pooling,
// tiny-LDS coefficient chain, 3 barriers, no bulk LDS traffic.
// C=12, T=10, H*W=28, K=3.
// Thread map: 128 threads per sample (2 samples / 256-thread block).
//   lane = tid&127, c = lane>>3 (0..15, active c<12), s4 = lane&7 (active <7).
// Each active thread owns the x column x[c][0..9][s4] in 10 f4 registers.
// Pooling: f4 hsum + 3x shfl_xor within aligned 8-lane groups.
// Apply: 3-tap conv from registers; stores are dense 64B-aligned per-t planes.

#define CC 12
#define TT 10
#define SAMPLE 3360
#define EPSF 1e-5f

typedef float f4 __attribute__((ext_vector_type(4)));

__global__ __launch_bounds__(256, 6) void tam_kernel(
    const float* __restrict__ x,
    const float* __restrict__ w_g1,
    const float* __restrict__ g1_gamma, const float* __restrict__ g1_beta,
    const float* __restrict__ g1_mean,  const float* __restrict__ g1_var,
    const float* __restrict__ w_g2,
    const float* __restrict__ w_l1,
    const float* __restrict__ l1_gamma, const float* __restrict__ l1_beta,
    const float* __restrict__ l1_mean,  const float* __restrict__ l1_var,
    const float* __restrict__ w_l2,
    float* __restrict__ out, int n_total)
{
    __shared__ float wg1[200], wg2[60], wl1[108], wl2[36];
    __shared__ float gs[20], gb[20], lsb[6];      // folded BN scale/bias
    __shared__ float pooled[2][120];
    __shared__ float zz[2][240];
    __shared__ float sa1[2][30];
    __shared__ float sact[2][120];
    __shared__ float skk[2][36];                  // k0[12] k1[12] k2[12]

    const int tid  = threadIdx.x;
    const int smp  = tid >> 7;                    // 0/1 sample within block
    const int lane = tid & 127;
    const int c    = lane >> 3;                   // 0..15
    const int s4   = lane & 7;                    // 0..7
    const int n    = blockIdx.x * 2 + smp;
    const bool alive = (c < CC) && (s4 < 7) && (n < n_total);

    // ---- issue x column loads first (10 outstanding per lane) ----
    const f4* xg = reinterpret_cast<const f4*>(x + (size_t)n * SAMPLE);
    f4 xv[TT];
    #pragma unroll
    for (int t = 0; t < TT; ++t) xv[t] = (f4)0.f;
    if (alive) {
        const int base = c * 70 + s4;             // f4 index: c*70 + t*7 + s4
        #pragma unroll
        for (int t = 0; t < TT; ++t) xv[t] = xg[base + t * 7];
    }

    // ---- weight staging + BN folding (hides under x-load latency) ----
    for (int i = tid; i < 200; i += 256) wg1[i] = w_g1[i];
    if (tid < 60)  wg2[tid] = w_g2[tid];
    if (tid < 108) wl1[tid] = w_l1[tid];
    if (tid < 36)  wl2[tid] = w_l2[tid];
    if (tid < 20) {
        const float s = rsqrtf(g1_var[tid] + EPSF) * g1_gamma[tid];
        gs[tid] = s; gb[tid] = g1_beta[tid] - g1_mean[tid] * s;
    } else if (tid < 23) {
        const int m = tid - 20;
        const float s = rsqrtf(l1_var[m] + EPSF) * l1_gamma[m];
        lsb[m] = s; lsb[3 + m] = l1_beta[m] - l1_mean[m] * s;
    }

    // ---- pooling: hsum + 8-lane shuffle reduce (no divergence here) ----
    #pragma unroll
    for (int t = 0; t < TT; ++t) {
        float h = xv[t].x + xv[t].y + xv[t].z + xv[t].w;
        h += __shfl_xor(h, 1, 8);
        h += __shfl_xor(h, 2, 8);
        h += __shfl_xor(h, 4, 8);
        if (s4 == 0 && c < CC) pooled[smp][c * TT + t] = h * (1.0f / 28.0f);
    }
    __syncthreads();   // barrier 1: weights + pooled ready

    // ---- coef A: G hidden (240 tasks) + L conv1 (30 tasks) per sample ----
    #pragma unroll
    for (int q = 0; q < 3; ++q) {
        const int task = lane + q * 128;
        if (task < 240) {
            const int cc = task / 20, j = task % 20;
            float s = 0.f;
            #pragma unroll
            for (int t = 0; t < TT; ++t)
                s += pooled[smp][cc * TT + t] * wg1[j * TT + t];
            zz[smp][task] = fmaxf(gs[j] * s + gb[j], 0.f);
        } else if (task < 270) {
            const int e = task - 240;
            const int m = e / TT, t = e % TT;
            float s = 0.f;
            #pragma unroll
            for (int cc = 0; cc < CC; ++cc) {
                #pragma unroll
                for (int k = 0; k < 3; ++k) {
                    const int t2 = t + k - 1;
                    if (t2 >= 0 && t2 < TT)
                        s += pooled[smp][cc * TT + t2] * wl1[(m * CC + cc) * 3 + k];
                }
            }
            sa1[smp][e] = fmaxf(lsb[m] * s + lsb[3 + m], 0.f);
        }
    }
    __syncthreads();   // barrier 2: zz + sa1 ready

    // ---- coef B: softmax scores (12 lanes) + conv2+sigmoid (120 lanes) ----
    if (lane < CC) {
        float sc0 = 0.f, sc1 = 0.f, sc2 = 0.f;
        #pragma unroll
        for (int j = 0; j < 20; ++j) {
            const float zj = zz[smp][lane * 20 + j];
            sc0 += zj * wg2[j];
            sc1 += zj * wg2[20 + j];
            sc2 += zj * wg2[40 + j];
        }
        const float mx = fmaxf(sc0, fmaxf(sc1, sc2));
        const float e0 = __expf(sc0 - mx), e1 = __expf(sc1 - mx), e2 = __expf(sc2 - mx);
        const float ri = 1.0f / (e0 + e1 + e2);
        skk[smp][lane]      = e0 * ri;
        skk[smp][12 + lane] = e1 * ri;
        skk[smp][24 + lane] = e2 * ri;
    }
    if (lane < 120) {
        const int cc = lane / TT, t = lane % TT;
        float s = 0.f;
        #pragma unroll
        for (int m = 0; m < 3; ++m) s += sa1[smp][m * TT + t] * wl2[cc * 3 + m];
        sact[smp][lane] = 1.0f / (1.0f + __expf(-s));
    }
    __syncthreads();   // barrier 3: kern + act ready

    // ---- apply from registers + dense transposed store ----
    if (alive) {
        f4* og = reinterpret_cast<f4*>(out + (size_t)n * SAMPLE);
        const float k0 = skk[smp][c];
        const float k1 = skk[smp][12 + c];
        const float k2 = skk[smp][24 + c];
        const float* ac = &sact[smp][c * TT];     // broadcast reads (same addr per c-group)
        #pragma unroll
        for (int t = 0; t < TT; ++t) {
            f4 r = (k1 * ac[t]) * xv[t];
            if (t > 0)      r += (k0 * ac[t - 1]) * xv[t - 1];
            if (t < TT - 1) r += (k2 * ac[t + 1]) * xv[t + 1];
            og[t * 84 + c * 7 + s4] = r;          // per-t: dense 1344B, 64B-aligned
        }
    }
}

extern "C" void kernel_launch(void* const* d_in, const int* in_sizes, int n_in,
                              void* d_out, int out_size, void* d_ws, size_t ws_size,
                              hipStream_t stream) {
    (void)n_in; (void)out_size; (void)d_ws; (void)ws_size;
    const float* x        = (const float*)d_in[0];
    const float* w_g1     = (const float*)d_in[1];
    const float* g1_gamma = (const float*)d_in[2];
    const float* g1_beta  = (const float*)d_in[3];
    const float* g1_mean  = (const float*)d_in[4];
    const float* g1_var   = (const float*)d_in[5];
    const float* w_g2     = (const float*)d_in[6];
    const float* w_l1     = (const float*)d_in[7];
    const float* l1_gamma = (const float*)d_in[8];
    const float* l1_beta  = (const float*)d_in[9];
    const float* l1_mean  = (const float*)d_in[10];
    const float* l1_var   = (const float*)d_in[11];
    const float* w_l2     = (const float*)d_in[12];
    float* out = (float*)d_out;

    const int n_total = in_sizes[0] / SAMPLE;     // 32768
    const int blocks  = (n_total + 1) / 2;        // 2 samples per block
    tam_kernel<<<blocks, 256, 0, stream>>>(
        x, w_g1, g1_gamma, g1_beta, g1_mean, g1_var, w_g2,
        w_l1, l1_gamma, l1_beta, l1_mean, l1_var, w_l2, out, n_total);
}

// Round 6
// 206.856 us; speedup vs baseline: 1.3525x; 1.1599x over previous
//
#include <hip/hip_runtime.h>

// TAM fused kernel round 6: R1 champion structure (block-per-sample, fully
// coalesced 1KB staging + stores) + NT stores (fix 1.5x WRITE inflation seen
// in R5 counters) + spread branch compute + LDS-staged folded weights.
// Plain loads kept on purpose: L3 retained ~25% of x in R5 (FETCH 336MB<440MB).
// C=12, T=10, H*W=28, K=3.

#define CC 12
#define TT 10
#define SAMPLE 3360
#define SAMPLE4 840
#define EPSF 1e-5f

typedef float f4 __attribute__((ext_vector_type(4)));

__global__ __launch_bounds__(256) void tam_kernel(
    const float* __restrict__ x,
    const float* __restrict__ w_g1,
    const float* __restrict__ g1_gamma, const float* __restrict__ g1_beta,
    const float* __restrict__ g1_mean,  const float* __restrict__ g1_var,
    const float* __restrict__ w_g2,
    const float* __restrict__ w_l1,
    const float* __restrict__ l1_gamma, const float* __restrict__ l1_beta,
    const float* __restrict__ l1_mean,  const float* __restrict__ l1_var,
    const float* __restrict__ w_l2,
    float* __restrict__ out)
{
    __shared__ f4    sx4[SAMPLE4];   // x in input order [c][t][s4]
    __shared__ float spool[120];     // pooled[c][t]
    __shared__ float sz[240];        // G hidden
    __shared__ float sa1[30];        // L hidden [m][t]
    __shared__ float skern[36];      // k0[12] k1[12] k2[12]
    __shared__ float sact[120];      // sigmoid gate [c][t]
    __shared__ float wg1s[200], wg2s[60], wl1s[108], wl2s[36];
    __shared__ float gs[20], gb[20], lsc[3], lbi[3];

    const int n   = blockIdx.x;
    const int tid = threadIdx.x;

    // ---- phase 1: stage sample (coalesced 1KB/instr, plain loads) ----
    const f4* xg = reinterpret_cast<const f4*>(x + (size_t)n * SAMPLE);
    for (int v = tid; v < SAMPLE4; v += 256) sx4[v] = xg[v];
    // weight staging + BN folding (hides under x loads)
    for (int i = tid; i < 200; i += 256) wg1s[i] = w_g1[i];
    if (tid < 60)  wg2s[tid] = w_g2[tid];
    if (tid < 108) wl1s[tid] = w_l1[tid];
    if (tid < 36)  wl2s[tid] = w_l2[tid];
    if (tid < 20) {
        const float s = rsqrtf(g1_var[tid] + EPSF) * g1_gamma[tid];
        gs[tid] = s; gb[tid] = g1_beta[tid] - g1_mean[tid] * s;
    } else if (tid < 23) {
        const int m = tid - 20;
        const float s = rsqrtf(l1_var[m] + EPSF) * l1_gamma[m];
        lsc[m] = s; lbi[m] = l1_beta[m] - l1_mean[m] * s;
    }
    __syncthreads();

    // ---- phase 2: spatial mean -> spool[c*10+t] (120 threads, 7 f4 each) ----
    if (tid < 120) {
        const f4* rp = sx4 + tid * 7;
        f4 a = rp[0];
        #pragma unroll
        for (int i = 1; i < 7; ++i) a += rp[i];
        spool[tid] = (a.x + a.y + a.z + a.w) * (1.0f / 28.0f);
    }
    __syncthreads();

    // ---- phase 3: G hidden (tasks 0..239) + L conv1 (tasks 240..269) ----
    for (int task = tid; task < 270; task += 256) {
        if (task < 240) {
            const int c = task / 20, j = task % 20;
            float s = 0.f;
            #pragma unroll
            for (int t = 0; t < TT; ++t)
                s += spool[c * TT + t] * wg1s[j * TT + t];
            sz[task] = fmaxf(gs[j] * s + gb[j], 0.f);
        } else {
            const int e = task - 240;
            const int m = e / TT, t = e % TT;
            float s = 0.f;
            #pragma unroll
            for (int c = 0; c < CC; ++c) {
                #pragma unroll
                for (int k = 0; k < 3; ++k) {
                    const int t2 = t + k - 1;
                    if (t2 >= 0 && t2 < TT)
                        s += spool[c * TT + t2] * wl1s[(m * CC + c) * 3 + k];
                }
            }
            sa1[e] = fmaxf(lsc[m] * s + lbi[m], 0.f);
        }
    }
    __syncthreads();

    // ---- phase 4: G softmax (wave 0) + L conv2+sigmoid (waves 1-2) ----
    if (tid < CC) {
        const int c = tid;
        float sc0 = 0.f, sc1 = 0.f, sc2 = 0.f;
        #pragma unroll
        for (int j = 0; j < 20; ++j) {
            const float zj = sz[c * 20 + j];
            sc0 += zj * wg2s[j];
            sc1 += zj * wg2s[20 + j];
            sc2 += zj * wg2s[40 + j];
        }
        const float mx = fmaxf(sc0, fmaxf(sc1, sc2));
        const float e0 = __expf(sc0 - mx), e1 = __expf(sc1 - mx), e2 = __expf(sc2 - mx);
        const float ri = 1.0f / (e0 + e1 + e2);
        skern[c]      = e0 * ri;
        skern[12 + c] = e1 * ri;
        skern[24 + c] = e2 * ri;
    }
    if (tid >= 64 && tid < 64 + 120) {
        const int idx = tid - 64;
        const int c = idx / TT, t = idx % TT;
        float s = 0.f;
        #pragma unroll
        for (int m = 0; m < 3; ++m) s += sa1[m * TT + t] * wl2s[c * 3 + m];
        sact[idx] = 1.0f / (1.0f + __expf(-s));
    }
    __syncthreads();

    // ---- phase 5: gated temporal conv, transposed coalesced NT store ----
    // out f4 vo = t*84 + c*7 + s4 ; taps at sx4 f4 = c*70 + t'*7 + s4.
    f4* og = reinterpret_cast<f4*>(out + (size_t)n * SAMPLE);
    for (int v = tid; v < SAMPLE4; v += 256) {
        const int t   = v / 84;
        const int rem = v % 84;
        const int c   = rem / 7;
        const int s4  = rem % 7;
        const int base = c * 70 + s4;
        const float k0 = skern[c];
        const float k1 = skern[12 + c];
        const float k2 = skern[24 + c];
        f4 acc = (k1 * sact[c * TT + t]) * sx4[base + t * 7];
        if (t > 0)
            acc += (k0 * sact[c * TT + t - 1]) * sx4[base + (t - 1) * 7];
        if (t < TT - 1)
            acc += (k2 * sact[c * TT + t + 1]) * sx4[base + (t + 1) * 7];
        __builtin_nontemporal_store(acc, og + v);
    }
}

extern "C" void kernel_launch(void* const* d_in, const int* in_sizes, int n_in,
                              void* d_out, int out_size, void* d_ws, size_t ws_size,
                              hipStream_t stream) {
    (void)n_in; (void)out_size; (void)d_ws; (void)ws_size;
    const float* x        = (const float*)d_in[0];
    const float* w_g1     = (const float*)d_in[1];
    const float* g1_gamma = (const float*)d_in[2];
    const float* g1_beta  = (const float*)d_in[3];
    const float* g1_mean  = (const float*)d_in[4];
    const float* g1_var   = (const float*)d_in[5];
    const float* w_g2     = (const float*)d_in[6];
    const float* w_l1     = (const float*)d_in[7];
    const float* l1_gamma = (const float*)d_in[8];
    const float* l1_beta  = (const float*)d_in[9];
    const float* l1_mean  = (const float*)d_in[10];
    const float* l1_var   = (const float*)d_in[11];
    const float* w_l2     = (const float*)d_in[12];
    float* out = (float*)d_out;

    const int n_total = in_sizes[0] / SAMPLE;  // 32768
    tam_kernel<<<n_total, 256, 0, stream>>>(
        x, w_g1, g1_gamma, g1_beta, g1_mean, g1_var, w_g2,
        w_l1, l1_gamma, l1_beta, l1_mean, l1_var, w_l2, out);
}